// Round 21
// baseline (34.593 us; speedup 1.0000x reference)
//
#include <hip/hip_runtime.h>
#include <hip/hip_bf16.h>

#define D_MODEL 1024
#define HEAD 64
#define TSEQ 2048
#define NB 4
#define BT (NB * TSEQ)

typedef __bf16 bf16x8 __attribute__((ext_vector_type(8)));
typedef __bf16 bf16x4 __attribute__((ext_vector_type(4)));
typedef float f32x4 __attribute__((ext_vector_type(4)));

#define LOG2E 1.44269504088896f
#define XPITCH 1032   // 1024 + 8 bf16 pad

__device__ inline unsigned pkbf(float a, float b) {
    union { __bf16 h[2]; unsigned u; } t;
    t.h[0] = (__bf16)a; t.h[1] = (__bf16)b;
    return t.u;
}

// ---------------------------------------------------------------------------
// Kernel 0 (ROUND 21): W -> fragment-major, WIDENED: 96 blocks x 512 thr
// (8x the threads of the 48x256 version; was a latency-bound ~4-6 us tail).
// Block (jt, c8): 16-col tile jt, 128 k-rows c8. Same wtf layout as R16-19.
// ---------------------------------------------------------------------------
__global__ __launch_bounds__(512) void wt_kernel(
    const float* __restrict__ Wq, const float* __restrict__ Wk,
    const float* __restrict__ Wv, __bf16* __restrict__ wtf)
{
    __shared__ float ws_[128][20];   // [k local][16 cols + pad4] = 10.2 KB

    int jt = blockIdx.x >> 3;        // 0..11
    int c8 = blockIdx.x & 7;         // 0..7 (128 k-rows each)
    int tsel = jt >> 2;
    int colbase = (jt & 3) * 16;
    const float* W = tsel == 0 ? Wq : (tsel == 1 ? Wk : Wv);

    int tid = threadIdx.x;
    {   // load 128 k-rows x 16 cols = 512 float4, one per thread
        int krow = tid >> 2, cg4 = tid & 3;
        float4 v = *(const float4*)(W + (size_t)(c8 * 128 + krow) * 64 + colbase + cg4 * 4);
        *(float4*)(&ws_[krow][cg4 * 4]) = v;
    }
    __syncthreads();
    if (tid < 256) {
        int kk = tid >> 6;           // local ktile 0..3
        int lane = tid & 63;
        int c16l = lane & 15, gl = lane >> 4;
        bf16x8 o;
#pragma unroll
        for (int i = 0; i < 8; ++i)
            o[i] = (__bf16)ws_[kk * 32 + gl * 8 + i][c16l];
        *(bf16x8*)(wtf + ((size_t)(jt * 32 + c8 * 4 + kk) * 64 + lane) * 8) = o;
    }
}

// ---------------------------------------------------------------------------
// Kernel 1: QKV GEMM (byte-identical to round 19; ~13.6 us).
// Grid 512 = (256 strips of 32 rows) x (2 col-halves), 2 blocks/CU.
// ---------------------------------------------------------------------------
__global__ __launch_bounds__(512, 4) void qkv_gemm(
    const float* __restrict__ x, const __bf16* __restrict__ wtf,
    const float* __restrict__ bq, const float* __restrict__ bk, const float* __restrict__ bv,
    __bf16* __restrict__ qs, __bf16* __restrict__ kf, __bf16* __restrict__ vf)
{
    __shared__ __align__(16) char lds_raw[66048];             // 64.5 KB
    __bf16 (*xls)[XPITCH]   = (__bf16(*)[XPITCH])lds_raw;     // staging
    f32x4 (*red)[4][6][64]  = (f32x4(*)[4][6][64])lds_raw;    // 48 KB reduce (reuse)

    int d = blockIdx.x;                 // 0..511
    int xcd = d & 7;
    int bi = d >> 3;                    // 0..63
    int strip = xcd * 32 + (bi >> 1);   // XCD i owns rows [i*1024,(i+1)*1024)
    int ch = bi & 1;
    int r0 = strip * 32;

    int tid = threadIdx.x;
    int w = tid >> 6;
    int rt = w >> 2;                    // row-tile 0..1
    int ks = w & 3;                     // K-quarter 0..3
    int lane = tid & 63;
    int c16 = lane & 15, g = lane >> 4;

    // ---- stage x[32][1024] -> LDS bf16, fully coalesced ----
#pragma unroll
    for (int i = 0; i < 16; ++i) {
        int f4 = tid + 512 * i;         // 0..8191
        int row = f4 >> 8;
        int k = (f4 & 255) * 4;
        float4 v = *(const float4*)(x + (size_t)(r0 + row) * D_MODEL + k);
        bf16x4 o;
        o[0] = (__bf16)v.x; o[1] = (__bf16)v.y;
        o[2] = (__bf16)v.z; o[3] = (__bf16)v.w;
        *(bf16x4*)(&xls[row][k]) = o;
    }
    __syncthreads();

    f32x4 acc[6];
#pragma unroll
    for (int j = 0; j < 6; ++j) acc[j] = (f32x4){0.f, 0.f, 0.f, 0.f};

    int arow = rt * 16 + c16;

#pragma unroll
    for (int kt = 0; kt < 8; ++kt) {
        int ktile = ks * 8 + kt;        // 0..31
        bf16x8 af = *(const bf16x8*)(&xls[arow][ktile * 32 + g * 8]);
        const __bf16* wb = wtf + ((size_t)ktile * 64 + lane) * 8;
#pragma unroll
        for (int j = 0; j < 6; ++j) {
            bf16x8 bfr = *(const bf16x8*)(wb + (size_t)(ch * 6 + j) * 32 * 64 * 8);
            acc[j] = __builtin_amdgcn_mfma_f32_16x16x32_bf16(af, bfr, acc[j], 0, 0, 0);
        }
    }

    __syncthreads();                    // all waves done reading xls
#pragma unroll
    for (int j = 0; j < 6; ++j) red[rt][ks][j][lane] = acc[j];
    __syncthreads();

    // ---- epilogue: wave (rt,ks) finalizes j=ks, and j=ks+4 if ks<2 ----
    int row0 = r0 + rt * 16 + g * 4;
    int b = row0 >> 11;
    int tloc = row0 & (TSEQ - 1);
    int ti = tloc >> 5;
    int fraghalf = (tloc >> 4) & 1;

#pragma unroll
    for (int pass = 0; pass < 2; ++pass) {
        if (pass == 1 && ks >= 2) break;
        int j = (pass == 0) ? ks : ks + 4;   // local coltile 0..5
        f32x4 s = red[rt][0][j][lane] + red[rt][1][j][lane]
                + red[rt][2][j][lane] + red[rt][3][j][lane];

        int col = ch * 96 + j * 16 + c16;    // global column 0..191
        int tsel = col >> 6;                 // 0=q 1=k 2=v
        int cm = col & 63;
        const float* bias = tsel == 0 ? bq : (tsel == 1 ? bk : bv);
        float bval = bias[cm];

        if (tsel == 0) {
#pragma unroll
            for (int r = 0; r < 4; ++r)
                qs[(size_t)(row0 + r) * HEAD + cm] = (__bf16)((s[r] + bval) * (0.03125f * LOG2E));
        } else if (tsel == 1) {
            int f = 2 * fraghalf + (cm >> 5);
            int gk = (cm & 31) >> 3;
            int ik = cm & 7;
            __bf16* base = kf + (((size_t)(b * 64 + ti) * 4 + f) * 64) * 8 + ik;
#pragma unroll
            for (int r = 0; r < 4; ++r)
                base[(size_t)((g * 4 + r) + 16 * gk) * 8] = (__bf16)(s[r] + bval);
        } else {
            int hh = cm >> 4;
            int gp = 2 * fraghalf + (g >> 1);
            bf16x4 o;
#pragma unroll
            for (int r = 0; r < 4; ++r) o[r] = (__bf16)(s[r] + bval);
            *(bf16x4*)(vf + (((size_t)(b * 64 + ti) * 4 + hh) * 64 + (cm & 15) + 16 * gp) * 8 + (g & 1) * 4) = o;
        }
    }
}

// ---------------------------------------------------------------------------
// Kernel 2: flash attention (byte-identical to round 17/19; ~10.9 us).
// ---------------------------------------------------------------------------
__global__ __launch_bounds__(512, 4) void attn_mfma(
    const __bf16* __restrict__ qs, const __bf16* __restrict__ kf,
    const __bf16* __restrict__ vf, float* __restrict__ out)
{
    __shared__ __align__(16) f32x4 ocomb[8][4][64];     // 32 KB [wave][hh][lane]
    __shared__ float mcomb[8][16];                      // [wave][qrow]
    __shared__ float lcomb[8][16];

    int d = blockIdx.x;
    int xcd = d & 7;
    int slot = d >> 3;                  // 0..63
    int b = xcd >> 1;
    int qt = ((xcd & 1) ? 127 : 126) - 2 * slot;   // heavy-first, parity split
    int qb = qt * 16;

    int tid = threadIdx.x;
    int w = tid >> 6;                   // 0..7
    int lane = tid & 63;
    int g = lane >> 4;
    int c16 = lane & 15;

    const __bf16* qsb = qs + (size_t)(b * TSEQ + qb) * HEAD;
    const __bf16* kfb = kf + (size_t)(b * 64) * 4 * 512;   // per-batch frag base
    const __bf16* vfb = vf + (size_t)(b * 64) * 4 * 512;

    bf16x8 qf0 = *(const bf16x8*)(qsb + c16 * HEAD + g * 8);
    bf16x8 qf1 = *(const bf16x8*)(qsb + c16 * HEAD + 32 + g * 8);

    f32x4 o0 = {0.f, 0.f, 0.f, 0.f}, o1 = o0, o2 = o0, o3 = o0;
    float m = -3.0e38f, l = 0.f;

    int nt = (qb + 47) >> 5;            // number of 32-key tiles
    int qrow = qb + c16;

    bf16x8 k00c, k01c, k10c, k11c;
    if (w < nt) {
        const __bf16* kt_ = kfb + (size_t)w * 4 * 512 + lane * 8;
        k00c = *(const bf16x8*)(kt_);
        k01c = *(const bf16x8*)(kt_ + 512);
        k10c = *(const bf16x8*)(kt_ + 1024);
        k11c = *(const bf16x8*)(kt_ + 1536);
    }

    for (int ti = w; ti < nt; ti += 8) {
        int kbase = ti * 32;

        const __bf16* vt_ = vfb + (size_t)ti * 4 * 512 + lane * 8;
        bf16x8 v0 = *(const bf16x8*)(vt_);
        bf16x8 v1 = *(const bf16x8*)(vt_ + 512);
        bf16x8 v2 = *(const bf16x8*)(vt_ + 1024);
        bf16x8 v3 = *(const bf16x8*)(vt_ + 1536);

        bool pf = (ti + 8) < nt;
        bf16x8 k00n, k01n, k10n, k11n;
        if (pf) {
            const __bf16* kn_ = kfb + (size_t)(ti + 8) * 4 * 512 + lane * 8;
            k00n = *(const bf16x8*)(kn_);
            k01n = *(const bf16x8*)(kn_ + 512);
            k10n = *(const bf16x8*)(kn_ + 1024);
            k11n = *(const bf16x8*)(kn_ + 1536);
        }

        f32x4 z = {0.f, 0.f, 0.f, 0.f};
        f32x4 s0 = __builtin_amdgcn_mfma_f32_16x16x32_bf16(k00c, qf0, z, 0, 0, 0);
        s0 = __builtin_amdgcn_mfma_f32_16x16x32_bf16(k01c, qf1, s0, 0, 0, 0);
        f32x4 s1 = __builtin_amdgcn_mfma_f32_16x16x32_bf16(k10c, qf0, z, 0, 0, 0);
        s1 = __builtin_amdgcn_mfma_f32_16x16x32_bf16(k11c, qf1, s1, 0, 0, 0);

        if (kbase + 31 > qb) {
#pragma unroll
            for (int r = 0; r < 4; ++r) {
                if (kbase + 4 * g + r > qrow)      s0[r] = -3.0e38f;
                if (kbase + 16 + 4 * g + r > qrow) s1[r] = -3.0e38f;
            }
        }

        float vmax = fmaxf(fmaxf(fmaxf(s0[0], s0[1]), fmaxf(s0[2], s0[3])),
                           fmaxf(fmaxf(s1[0], s1[1]), fmaxf(s1[2], s1[3])));
        vmax = fmaxf(vmax, __shfl_xor(vmax, 16, 64));
        vmax = fmaxf(vmax, __shfl_xor(vmax, 32, 64));
        float mn = fmaxf(m, vmax);
        float al = exp2f(m - mn);
        m = mn;

        float p0[4], p1[4];
        float rsum = 0.f;
#pragma unroll
        for (int r = 0; r < 4; ++r) {
            p0[r] = exp2f(s0[r] - m);
            p1[r] = exp2f(s1[r] - m);
            rsum += p0[r] + p1[r];
        }
        rsum += __shfl_xor(rsum, 16, 64);
        rsum += __shfl_xor(rsum, 32, 64);
        l = l * al + rsum;
        o0 *= al; o1 *= al; o2 *= al; o3 *= al;

        unsigned pk[4];
        pk[0] = pkbf(p0[0], p0[1]); pk[1] = pkbf(p0[2], p0[3]);
        pk[2] = pkbf(p1[0], p1[1]); pk[3] = pkbf(p1[2], p1[3]);

        union { unsigned u[4]; bf16x8 v; } pb;
#pragma unroll
        for (int t = 0; t < 4; ++t) {
            int srcl = c16 + 16 * ((2 * g + (t >> 1)) & 3);
            unsigned lo = (unsigned)__shfl((int)pk[t & 1], srcl, 64);
            unsigned hi = (unsigned)__shfl((int)pk[2 + (t & 1)], srcl, 64);
            pb.u[t] = (g < 2) ? lo : hi;
        }

        o0 = __builtin_amdgcn_mfma_f32_16x16x32_bf16(v0, pb.v, o0, 0, 0, 0);
        o1 = __builtin_amdgcn_mfma_f32_16x16x32_bf16(v1, pb.v, o1, 0, 0, 0);
        o2 = __builtin_amdgcn_mfma_f32_16x16x32_bf16(v2, pb.v, o2, 0, 0, 0);
        o3 = __builtin_amdgcn_mfma_f32_16x16x32_bf16(v3, pb.v, o3, 0, 0, 0);

        if (pf) { k00c = k00n; k01c = k01n; k10c = k10n; k11c = k11n; }
    }

    ocomb[w][0][lane] = o0;
    ocomb[w][1][lane] = o1;
    ocomb[w][2][lane] = o2;
    ocomb[w][3][lane] = o3;
    if (g == 0) {
        mcomb[w][c16] = m;
        lcomb[w][c16] = l;
    }
    __syncthreads();

    if (w < 4) {
        float M = mcomb[0][c16];
#pragma unroll
        for (int sw = 1; sw < 8; ++sw) M = fmaxf(M, mcomb[sw][c16]);
        f32x4 O = {0.f, 0.f, 0.f, 0.f};
        float L = 0.f;
#pragma unroll
        for (int sw = 0; sw < 8; ++sw) {
            float e = exp2f(mcomb[sw][c16] - M);
            L += lcomb[sw][c16] * e;
            f32x4 po = ocomb[sw][w][lane];
            O[0] += po[0] * e; O[1] += po[1] * e;
            O[2] += po[2] * e; O[3] += po[3] * e;
        }
        float rcp = 1.0f / L;
        f32x4 res = {O[0] * rcp, O[1] * rcp, O[2] * rcp, O[3] * rcp};
        *(f32x4*)(out + (size_t)(b * TSEQ + qb + c16) * HEAD + w * 16 + g * 4) = res;
    }
}

extern "C" void kernel_launch(void* const* d_in, const int* in_sizes, int n_in,
                              void* d_out, int out_size, void* d_ws, size_t ws_size,
                              hipStream_t stream) {
    const float* x  = (const float*)d_in[0];
    const float* Wk = (const float*)d_in[1];
    const float* Wq = (const float*)d_in[2];
    const float* Wv = (const float*)d_in[3];
    const float* bk = (const float*)d_in[4];
    const float* bq = (const float*)d_in[5];
    const float* bv = (const float*)d_in[6];
    float* out = (float*)d_out;

    __bf16* qs  = (__bf16*)d_ws;                       // [BT][64]           1 MB
    __bf16* kf  = qs + (size_t)BT * HEAD;              // [NB][64][4][64][8] 1 MB
    __bf16* vf  = kf + (size_t)BT * HEAD;              // [NB][64][4][64][8] 1 MB
    __bf16* wtf = vf + (size_t)BT * HEAD;              // [12][32][64][8]  384 KB

    wt_kernel<<<96, 512, 0, stream>>>(Wq, Wk, Wv, wtf);
    qkv_gemm<<<512, 512, 0, stream>>>(x, wtf, bq, bk, bv, qs, kf, vf);
    attn_mfma<<<512, 512, 0, stream>>>(qs, kf, vf, out);
}

// Round 22
// 34.419 us; speedup vs baseline: 1.0051x; 1.0051x over previous
//
#include <hip/hip_runtime.h>
#include <hip/hip_bf16.h>

#define D_MODEL 1024
#define HEAD 64
#define TSEQ 2048
#define NB 4
#define BT (NB * TSEQ)

typedef __bf16 bf16x8 __attribute__((ext_vector_type(8)));
typedef __bf16 bf16x4 __attribute__((ext_vector_type(4)));
typedef float f32x4 __attribute__((ext_vector_type(4)));

#define LOG2E 1.44269504088896f
#define XPITCH 1032   // 1024 + 8 bf16 pad

__device__ inline unsigned pkbf(float a, float b) {
    union { __bf16 h[2]; unsigned u; } t;
    t.h[0] = (__bf16)a; t.h[1] = (__bf16)b;
    return t.u;
}

// ---------------------------------------------------------------------------
// Kernel 0: W -> fragment-major (96 blocks x 512 thr; byte-identical to R21).
// ---------------------------------------------------------------------------
__global__ __launch_bounds__(512) void wt_kernel(
    const float* __restrict__ Wq, const float* __restrict__ Wk,
    const float* __restrict__ Wv, __bf16* __restrict__ wtf)
{
    __shared__ float ws_[128][20];

    int jt = blockIdx.x >> 3;        // 0..11
    int c8 = blockIdx.x & 7;         // 0..7
    int tsel = jt >> 2;
    int colbase = (jt & 3) * 16;
    const float* W = tsel == 0 ? Wq : (tsel == 1 ? Wk : Wv);

    int tid = threadIdx.x;
    {
        int krow = tid >> 2, cg4 = tid & 3;
        float4 v = *(const float4*)(W + (size_t)(c8 * 128 + krow) * 64 + colbase + cg4 * 4);
        *(float4*)(&ws_[krow][cg4 * 4]) = v;
    }
    __syncthreads();
    if (tid < 256) {
        int kk = tid >> 6;
        int lane = tid & 63;
        int c16l = lane & 15, gl = lane >> 4;
        bf16x8 o;
#pragma unroll
        for (int i = 0; i < 8; ++i)
            o[i] = (__bf16)ws_[kk * 32 + gl * 8 + i][c16l];
        *(bf16x8*)(wtf + ((size_t)(jt * 32 + c8 * 4 + kk) * 64 + lane) * 8) = o;
    }
}

// ---------------------------------------------------------------------------
// Kernel 1 (ROUND 22): QKV GEMM — staging split into issue-early (all 16
// global_load_dwordx4 first, 64 VGPR) / convert+ds_write-late (T14 / G15).
// Was: interleaved load->cvt->ds_write = 16 serialized vmcnt round-trips.
// Everything else byte-identical to R19/R21.
// ---------------------------------------------------------------------------
__global__ __launch_bounds__(512, 4) void qkv_gemm(
    const float* __restrict__ x, const __bf16* __restrict__ wtf,
    const float* __restrict__ bq, const float* __restrict__ bk, const float* __restrict__ bv,
    __bf16* __restrict__ qs, __bf16* __restrict__ kf, __bf16* __restrict__ vf)
{
    __shared__ __align__(16) char lds_raw[66048];             // 64.5 KB
    __bf16 (*xls)[XPITCH]   = (__bf16(*)[XPITCH])lds_raw;     // staging
    f32x4 (*red)[4][6][64]  = (f32x4(*)[4][6][64])lds_raw;    // 48 KB reduce (reuse)

    int d = blockIdx.x;                 // 0..511
    int xcd = d & 7;
    int bi = d >> 3;                    // 0..63
    int strip = xcd * 32 + (bi >> 1);   // XCD i owns rows [i*1024,(i+1)*1024)
    int ch = bi & 1;
    int r0 = strip * 32;

    int tid = threadIdx.x;
    int w = tid >> 6;
    int rt = w >> 2;                    // row-tile 0..1
    int ks = w & 3;                     // K-quarter 0..3
    int lane = tid & 63;
    int c16 = lane & 15, g = lane >> 4;

    // ---- stage x[32][1024]: ISSUE all 16 loads first, then cvt+write ----
    float4 xr[16];
#pragma unroll
    for (int i = 0; i < 16; ++i) {
        int f4 = tid + 512 * i;         // 0..8191
        int row = f4 >> 8;
        int k = (f4 & 255) * 4;
        xr[i] = *(const float4*)(x + (size_t)(r0 + row) * D_MODEL + k);
    }
#pragma unroll
    for (int i = 0; i < 16; ++i) {
        int f4 = tid + 512 * i;
        int row = f4 >> 8;
        int k = (f4 & 255) * 4;
        bf16x4 o;
        o[0] = (__bf16)xr[i].x; o[1] = (__bf16)xr[i].y;
        o[2] = (__bf16)xr[i].z; o[3] = (__bf16)xr[i].w;
        *(bf16x4*)(&xls[row][k]) = o;
    }
    __syncthreads();

    f32x4 acc[6];
#pragma unroll
    for (int j = 0; j < 6; ++j) acc[j] = (f32x4){0.f, 0.f, 0.f, 0.f};

    int arow = rt * 16 + c16;

#pragma unroll
    for (int kt = 0; kt < 8; ++kt) {
        int ktile = ks * 8 + kt;        // 0..31
        bf16x8 af = *(const bf16x8*)(&xls[arow][ktile * 32 + g * 8]);
        const __bf16* wb = wtf + ((size_t)ktile * 64 + lane) * 8;
#pragma unroll
        for (int j = 0; j < 6; ++j) {
            bf16x8 bfr = *(const bf16x8*)(wb + (size_t)(ch * 6 + j) * 32 * 64 * 8);
            acc[j] = __builtin_amdgcn_mfma_f32_16x16x32_bf16(af, bfr, acc[j], 0, 0, 0);
        }
    }

    __syncthreads();                    // all waves done reading xls
#pragma unroll
    for (int j = 0; j < 6; ++j) red[rt][ks][j][lane] = acc[j];
    __syncthreads();

    // ---- epilogue: wave (rt,ks) finalizes j=ks, and j=ks+4 if ks<2 ----
    int row0 = r0 + rt * 16 + g * 4;
    int b = row0 >> 11;
    int tloc = row0 & (TSEQ - 1);
    int ti = tloc >> 5;
    int fraghalf = (tloc >> 4) & 1;

#pragma unroll
    for (int pass = 0; pass < 2; ++pass) {
        if (pass == 1 && ks >= 2) break;
        int j = (pass == 0) ? ks : ks + 4;   // local coltile 0..5
        f32x4 s = red[rt][0][j][lane] + red[rt][1][j][lane]
                + red[rt][2][j][lane] + red[rt][3][j][lane];

        int col = ch * 96 + j * 16 + c16;    // global column 0..191
        int tsel = col >> 6;                 // 0=q 1=k 2=v
        int cm = col & 63;
        const float* bias = tsel == 0 ? bq : (tsel == 1 ? bk : bv);
        float bval = bias[cm];

        if (tsel == 0) {
#pragma unroll
            for (int r = 0; r < 4; ++r)
                qs[(size_t)(row0 + r) * HEAD + cm] = (__bf16)((s[r] + bval) * (0.03125f * LOG2E));
        } else if (tsel == 1) {
            int f = 2 * fraghalf + (cm >> 5);
            int gk = (cm & 31) >> 3;
            int ik = cm & 7;
            __bf16* base = kf + (((size_t)(b * 64 + ti) * 4 + f) * 64) * 8 + ik;
#pragma unroll
            for (int r = 0; r < 4; ++r)
                base[(size_t)((g * 4 + r) + 16 * gk) * 8] = (__bf16)(s[r] + bval);
        } else {
            int hh = cm >> 4;
            int gp = 2 * fraghalf + (g >> 1);
            bf16x4 o;
#pragma unroll
            for (int r = 0; r < 4; ++r) o[r] = (__bf16)(s[r] + bval);
            *(bf16x4*)(vf + (((size_t)(b * 64 + ti) * 4 + hh) * 64 + (cm & 15) + 16 * gp) * 8 + (g & 1) * 4) = o;
        }
    }
}

// ---------------------------------------------------------------------------
// Kernel 2: flash attention (byte-identical to rounds 17/19/21).
// ---------------------------------------------------------------------------
__global__ __launch_bounds__(512, 4) void attn_mfma(
    const __bf16* __restrict__ qs, const __bf16* __restrict__ kf,
    const __bf16* __restrict__ vf, float* __restrict__ out)
{
    __shared__ __align__(16) f32x4 ocomb[8][4][64];     // 32 KB [wave][hh][lane]
    __shared__ float mcomb[8][16];                      // [wave][qrow]
    __shared__ float lcomb[8][16];

    int d = blockIdx.x;
    int xcd = d & 7;
    int slot = d >> 3;                  // 0..63
    int b = xcd >> 1;
    int qt = ((xcd & 1) ? 127 : 126) - 2 * slot;   // heavy-first, parity split
    int qb = qt * 16;

    int tid = threadIdx.x;
    int w = tid >> 6;                   // 0..7
    int lane = tid & 63;
    int g = lane >> 4;
    int c16 = lane & 15;

    const __bf16* qsb = qs + (size_t)(b * TSEQ + qb) * HEAD;
    const __bf16* kfb = kf + (size_t)(b * 64) * 4 * 512;   // per-batch frag base
    const __bf16* vfb = vf + (size_t)(b * 64) * 4 * 512;

    bf16x8 qf0 = *(const bf16x8*)(qsb + c16 * HEAD + g * 8);
    bf16x8 qf1 = *(const bf16x8*)(qsb + c16 * HEAD + 32 + g * 8);

    f32x4 o0 = {0.f, 0.f, 0.f, 0.f}, o1 = o0, o2 = o0, o3 = o0;
    float m = -3.0e38f, l = 0.f;

    int nt = (qb + 47) >> 5;            // number of 32-key tiles
    int qrow = qb + c16;

    bf16x8 k00c, k01c, k10c, k11c;
    if (w < nt) {
        const __bf16* kt_ = kfb + (size_t)w * 4 * 512 + lane * 8;
        k00c = *(const bf16x8*)(kt_);
        k01c = *(const bf16x8*)(kt_ + 512);
        k10c = *(const bf16x8*)(kt_ + 1024);
        k11c = *(const bf16x8*)(kt_ + 1536);
    }

    for (int ti = w; ti < nt; ti += 8) {
        int kbase = ti * 32;

        const __bf16* vt_ = vfb + (size_t)ti * 4 * 512 + lane * 8;
        bf16x8 v0 = *(const bf16x8*)(vt_);
        bf16x8 v1 = *(const bf16x8*)(vt_ + 512);
        bf16x8 v2 = *(const bf16x8*)(vt_ + 1024);
        bf16x8 v3 = *(const bf16x8*)(vt_ + 1536);

        bool pf = (ti + 8) < nt;
        bf16x8 k00n, k01n, k10n, k11n;
        if (pf) {
            const __bf16* kn_ = kfb + (size_t)(ti + 8) * 4 * 512 + lane * 8;
            k00n = *(const bf16x8*)(kn_);
            k01n = *(const bf16x8*)(kn_ + 512);
            k10n = *(const bf16x8*)(kn_ + 1024);
            k11n = *(const bf16x8*)(kn_ + 1536);
        }

        f32x4 z = {0.f, 0.f, 0.f, 0.f};
        f32x4 s0 = __builtin_amdgcn_mfma_f32_16x16x32_bf16(k00c, qf0, z, 0, 0, 0);
        s0 = __builtin_amdgcn_mfma_f32_16x16x32_bf16(k01c, qf1, s0, 0, 0, 0);
        f32x4 s1 = __builtin_amdgcn_mfma_f32_16x16x32_bf16(k10c, qf0, z, 0, 0, 0);
        s1 = __builtin_amdgcn_mfma_f32_16x16x32_bf16(k11c, qf1, s1, 0, 0, 0);

        if (kbase + 31 > qb) {
#pragma unroll
            for (int r = 0; r < 4; ++r) {
                if (kbase + 4 * g + r > qrow)      s0[r] = -3.0e38f;
                if (kbase + 16 + 4 * g + r > qrow) s1[r] = -3.0e38f;
            }
        }

        float vmax = fmaxf(fmaxf(fmaxf(s0[0], s0[1]), fmaxf(s0[2], s0[3])),
                           fmaxf(fmaxf(s1[0], s1[1]), fmaxf(s1[2], s1[3])));
        vmax = fmaxf(vmax, __shfl_xor(vmax, 16, 64));
        vmax = fmaxf(vmax, __shfl_xor(vmax, 32, 64));
        float mn = fmaxf(m, vmax);
        float al = exp2f(m - mn);
        m = mn;

        float p0[4], p1[4];
        float rsum = 0.f;
#pragma unroll
        for (int r = 0; r < 4; ++r) {
            p0[r] = exp2f(s0[r] - m);
            p1[r] = exp2f(s1[r] - m);
            rsum += p0[r] + p1[r];
        }
        rsum += __shfl_xor(rsum, 16, 64);
        rsum += __shfl_xor(rsum, 32, 64);
        l = l * al + rsum;
        o0 *= al; o1 *= al; o2 *= al; o3 *= al;

        unsigned pk[4];
        pk[0] = pkbf(p0[0], p0[1]); pk[1] = pkbf(p0[2], p0[3]);
        pk[2] = pkbf(p1[0], p1[1]); pk[3] = pkbf(p1[2], p1[3]);

        union { unsigned u[4]; bf16x8 v; } pb;
#pragma unroll
        for (int t = 0; t < 4; ++t) {
            int srcl = c16 + 16 * ((2 * g + (t >> 1)) & 3);
            unsigned lo = (unsigned)__shfl((int)pk[t & 1], srcl, 64);
            unsigned hi = (unsigned)__shfl((int)pk[2 + (t & 1)], srcl, 64);
            pb.u[t] = (g < 2) ? lo : hi;
        }

        o0 = __builtin_amdgcn_mfma_f32_16x16x32_bf16(v0, pb.v, o0, 0, 0, 0);
        o1 = __builtin_amdgcn_mfma_f32_16x16x32_bf16(v1, pb.v, o1, 0, 0, 0);
        o2 = __builtin_amdgcn_mfma_f32_16x16x32_bf16(v2, pb.v, o2, 0, 0, 0);
        o3 = __builtin_amdgcn_mfma_f32_16x16x32_bf16(v3, pb.v, o3, 0, 0, 0);

        if (pf) { k00c = k00n; k01c = k01n; k10c = k10n; k11c = k11n; }
    }

    ocomb[w][0][lane] = o0;
    ocomb[w][1][lane] = o1;
    ocomb[w][2][lane] = o2;
    ocomb[w][3][lane] = o3;
    if (g == 0) {
        mcomb[w][c16] = m;
        lcomb[w][c16] = l;
    }
    __syncthreads();

    if (w < 4) {
        float M = mcomb[0][c16];
#pragma unroll
        for (int sw = 1; sw < 8; ++sw) M = fmaxf(M, mcomb[sw][c16]);
        f32x4 O = {0.f, 0.f, 0.f, 0.f};
        float L = 0.f;
#pragma unroll
        for (int sw = 0; sw < 8; ++sw) {
            float e = exp2f(mcomb[sw][c16] - M);
            L += lcomb[sw][c16] * e;
            f32x4 po = ocomb[sw][w][lane];
            O[0] += po[0] * e; O[1] += po[1] * e;
            O[2] += po[2] * e; O[3] += po[3] * e;
        }
        float rcp = 1.0f / L;
        f32x4 res = {O[0] * rcp, O[1] * rcp, O[2] * rcp, O[3] * rcp};
        *(f32x4*)(out + (size_t)(b * TSEQ + qb + c16) * HEAD + w * 16 + g * 4) = res;
    }
}

extern "C" void kernel_launch(void* const* d_in, const int* in_sizes, int n_in,
                              void* d_out, int out_size, void* d_ws, size_t ws_size,
                              hipStream_t stream) {
    const float* x  = (const float*)d_in[0];
    const float* Wk = (const float*)d_in[1];
    const float* Wq = (const float*)d_in[2];
    const float* Wv = (const float*)d_in[3];
    const float* bk = (const float*)d_in[4];
    const float* bq = (const float*)d_in[5];
    const float* bv = (const float*)d_in[6];
    float* out = (float*)d_out;

    __bf16* qs  = (__bf16*)d_ws;                       // [BT][64]           1 MB
    __bf16* kf  = qs + (size_t)BT * HEAD;              // [NB][64][4][64][8] 1 MB
    __bf16* vf  = kf + (size_t)BT * HEAD;              // [NB][64][4][64][8] 1 MB
    __bf16* wtf = vf + (size_t)BT * HEAD;              // [12][32][64][8]  384 KB

    wt_kernel<<<96, 512, 0, stream>>>(Wq, Wk, Wv, wtf);
    qkv_gemm<<<512, 512, 0, stream>>>(x, wtf, bq, bk, bv, qs, kf, vf);
    attn_mfma<<<512, 512, 0, stream>>>(qs, kf, vf, out);
}